// Round 3
// 434.173 us; speedup vs baseline: 1.2028x; 1.2028x over previous
//
#include <hip/hip_runtime.h>
#include <hip/hip_fp16.h>

// LSTM: B=256, T=1024, I=64, H=25 (4H=100), O=64. fp32 in/out.
//
// R1 theory: lstm_rec5 (309us, 724 cyc/step) was register-pressure bound:
//   104 weight VGPRs vs 84 allocated -> spill traffic on the single wave/CU.
// lstm_rec6:
//   - gates split across wave halves: lanes 0..31 own (i,g) of unit r,
//     lanes 32..63 own (f,o).  52 weight VGPRs, 26 pk_fma/step (was 52).
//   - exp2 scale folding: k1 stores gws pre-scaled by -log2e (sigmoid cols)
//     / -2log2e (tanh col); k2 scales its W_hh copy identically -> raw
//     v_exp_f32 per activation, zero per-step scale muls.
//   - gws layout: cols 0..49 = (i,g) interleaved per unit, 50..99 = (f,o)
//     -> one dwordx2 per lane per step, 8-deep prefetch ring.
//   - unconditional h store (junk lanes hit consumed cols 25..63 of row t).
// R3 FIX: v_permlane32_swap_b32 swaps a[32:63]<->b[0:31]; a's LOW lanes are
//   unchanged -> returning `a` gave low lanes their OWN value (no swap):
//   c = I*c + I*G, h = G*tanh(c) -> absmax 1.13 (matches R2 failure).
//   Replace with __shfl_xor(x, 32, 64) (ds_bpermute, semantics guaranteed).
// k3: 64 rows/block (4x less W_fc restaging).

#define Bn 256
#define Tn 1024
#define In 64
#define Hn 25
#define Gn 100
#define On 64
#define BT (Bn * Tn)
#define ROW 100

#define SCL_S -1.44269504089f   // -log2(e)   : sigmoid gates (i,f,o)
#define SCL_T -2.88539008178f   // -2*log2(e) : tanh gate (g)

typedef __attribute__((ext_vector_type(8))) short short8;
typedef __attribute__((ext_vector_type(4))) float f32x4;
typedef __attribute__((ext_vector_type(2))) float f32x2;

__device__ __forceinline__ float frcp(float x) { return __builtin_amdgcn_rcpf(x); }
__device__ __forceinline__ float ex2(float x) {
    // raw v_exp_f32 (2^x); s_nop 1 covers any trans->VALU consumer hazard
    // the compiler cannot see through the asm block.
    float r;
    asm("v_exp_f32 %0, %1\n\ts_nop 1" : "=v"(r) : "v"(x));
    return r;
}
__device__ __forceinline__ float bcast(float v, int lane) {
    return __int_as_float(__builtin_amdgcn_readlane(__float_as_int(v), lane));
}
__device__ __forceinline__ float xswap(float x) {
    // lane l <-> lane l^32 exchange, semantics-guaranteed (ds_bpermute).
    return __shfl_xor(x, 32, 64);
}
__device__ __forceinline__ short f2bf(float f) {   // RNE fp32 -> bf16 bits
    unsigned u = __float_as_uint(f);
    unsigned r = (u + 0x7FFFu + ((u >> 16) & 1u)) >> 16;
    return (short)r;
}

// gws column map: n<50: unit n>>1, gate i (even) / g (odd);
//                 n>=50: m=n-50, unit m>>1, gate f (even) / o (odd).
__device__ __forceinline__ void colmap(int n, int& g, float& scl) {
    if (n < 50) {
        const int r = n >> 1;
        g = ((n & 1) ? 2 : 0) * Hn + r;
        scl = (n & 1) ? SCL_T : SCL_S;
    } else {
        const int m = n - 50, r = m >> 1;
        g = ((m & 1) ? 3 : 1) * Hn + r;
        scl = SCL_S;
    }
}

// ---------------- kernel 1: input GEMM via MFMA ----------------
template <typename ST>
__global__ __launch_bounds__(256, 4)
void gates_mfma(const float* __restrict__ x, const float* __restrict__ W_ih,
                const float* __restrict__ b_ih, const float* __restrict__ b_hh,
                ST* __restrict__ gws) {
    __shared__ short lA[64 * 72];
    __shared__ short lB[112 * 72];
    __shared__ float lbias[112];

    const int tid = threadIdx.x;
    const size_t row0 = (size_t)blockIdx.x * 64;

    for (int i = tid; i < 64 * 64; i += 256) {
        const int r = i >> 6, k = i & 63;
        lA[r * 72 + k] = f2bf(x[(row0 + r) * In + k]);
    }
    for (int i = tid; i < 112 * 64; i += 256) {
        const int n = i >> 6, k = i & 63;
        float v = 0.f;
        if (n < Gn) {
            int g; float scl;
            colmap(n, g, scl);
            v = W_ih[(size_t)g * In + k] * scl;   // scale folded pre-bf16
        }
        lB[n * 72 + k] = f2bf(v);
    }
    if (tid < 112) {
        float v = 0.f;
        if (tid < Gn) {
            int g; float scl;
            colmap(tid, g, scl);
            v = (b_ih[g] + b_hh[g]) * scl;
        }
        lbias[tid] = v;
    }
    __syncthreads();

    const int wave = tid >> 6;
    const int lane = tid & 63;
    const int quad = lane >> 4;
    const int l16  = lane & 15;
    const int arow = wave * 16 + l16;

    const short8 a0 = *(const short8*)&lA[arow * 72 + 0  + quad * 8];
    const short8 a1 = *(const short8*)&lA[arow * 72 + 32 + quad * 8];

#pragma unroll
    for (int nt = 0; nt < 7; ++nt) {
        const int col = nt * 16 + l16;
        const short8 b0 = *(const short8*)&lB[col * 72 + 0  + quad * 8];
        const short8 b1 = *(const short8*)&lB[col * 72 + 32 + quad * 8];
        const float bias = lbias[col];
        f32x4 acc = {bias, bias, bias, bias};
        acc = __builtin_amdgcn_mfma_f32_16x16x32_bf16(a0, b0, acc, 0, 0, 0);
        acc = __builtin_amdgcn_mfma_f32_16x16x32_bf16(a1, b1, acc, 0, 0, 0);
        if (col < Gn) {
#pragma unroll
            for (int i = 0; i < 4; ++i) {
                const size_t grow = row0 + wave * 16 + quad * 4 + i;
                gws[grow * ROW + col] = (ST)acc[i];
            }
        }
    }
}

// ---------------- kernel 2: recurrence, 1 wave / batch ----------------
template <typename ST> struct G2;
template <> struct G2<float> {
    static __device__ __forceinline__ float2 ld(const float* p) {
        return *(const float2*)p;
    }
};
template <> struct G2<__half> {
    static __device__ __forceinline__ float2 ld(const __half* p) {
        ushort2 u = *(const ushort2*)p;
        __half a, b;
        *(unsigned short*)&a = u.x; *(unsigned short*)&b = u.y;
        return make_float2((float)a, (float)b);
    }
};

__device__ __forceinline__ float dot25v(const f32x2* w, const f32x2* hv) {
    f32x2 a0 = w[0] * hv[0];          // pk_mul start: no acc-init movs
    f32x2 a1 = w[1] * hv[1];
#pragma unroll
    for (int j = 2; j < 13; j += 2) a0 += w[j] * hv[j];   // 6 pk_fma, chain 7
#pragma unroll
    for (int j = 3; j < 13; j += 2) a1 += w[j] * hv[j];   // 5 pk_fma, chain 6
    f32x2 s = a0 + a1;
    return s.x + s.y;
}

template <typename ST>
__global__ __launch_bounds__(64, 1)
void lstm_rec6(ST* __restrict__ gws, const float* __restrict__ W_hh) {
    const int lane = threadIdx.x;
    const bool lo  = lane < 32;
    const int rr   = min(lane & 31, Hn - 1);
    const int b    = blockIdx.x;

    // this lane's two gates: A = i (lo) / f (hi), B = g (lo) / o (hi)
    const float sclA = SCL_S;
    const float sclB = lo ? SCL_T : SCL_S;
    const float sB   = lo ? 2.f : 1.f;     // tanh = 2*sigm(2x)-1
    const float dB   = lo ? -1.f : 0.f;
    const float* rowA = W_hh + (size_t)((lo ? 0 : 1) * Hn + rr) * Hn;
    const float* rowB = W_hh + (size_t)((lo ? 2 : 3) * Hn + rr) * Hn;

    f32x2 wA[13], wB[13];   // 52 VGPRs of weights (was 104)
#pragma unroll
    for (int j = 0; j < 13; ++j) {
        const int j0 = 2 * j, j1 = 2 * j + 1;
        wA[j].x = rowA[j0] * sclA;
        wA[j].y = (j1 < Hn) ? rowA[j1] * sclA : 0.f;
        wB[j].x = rowB[j0] * sclB;
        wB[j].y = (j1 < Hn) ? rowB[j1] * sclB : 0.f;
    }

    const int coff = 2 * rr + (lo ? 0 : 50);                 // element offset in row
    const ST* gp = gws + (size_t)b * Tn * ROW + coff;        // dwordx2 gate loads
    ST*       hw = gws + (size_t)b * Tn * ROW + lane;        // h stores

    f32x2 hv[13];
#pragma unroll
    for (int j = 0; j < 13; ++j) hv[j] = (f32x2){0.f, 0.f};
    float c = 0.f;

    float2 ring[8];                                          // 8-deep prefetch
#pragma unroll
    for (int s = 0; s < 8; ++s) ring[s] = G2<ST>::ld(gp + (size_t)s * ROW);

#pragma unroll 1
    for (int t0 = 0; t0 < Tn; t0 += 8) {
        // last block re-loads rows Tn-8..Tn-1 (never consumed; harmless)
        const int tp0 = (t0 + 8 <= Tn - 8) ? (t0 + 8) : (Tn - 8);
#pragma unroll
        for (int s = 0; s < 8; ++s) {
            const int t = t0 + s;

            const float2 nxt = G2<ST>::ld(gp + (size_t)(tp0 + s) * ROW);

            float aA = dot25v(wA, hv);
            float aB = dot25v(wB, hv);
            aA += ring[s].x;            // vmcnt wait lands here, after the dot
            aB += ring[s].y;
            ring[s] = nxt;

            const float actA = frcp(1.f + ex2(aA));            // I (lo) / F (hi)
            const float actB = sB * frcp(1.f + ex2(aB)) + dB;  // G (lo) / O (hi)
            const float Fg = xswap(actA);   // low lanes: F of same unit
            const float Og = xswap(actB);   // low lanes: O of same unit
            c = Fg * c + actA * actB;       // valid in lanes 0..24
            const float th = 2.f * frcp(1.f + ex2(c * SCL_T)) - 1.f;  // tanh(c)
            const float h  = Og * th;

            // lanes 0..24 write h into cols 0..24 of (consumed) row t;
            // lanes 25..63 write junk into consumed cols 25..63 - harmless.
            hw[(size_t)t * ROW] = (ST)h;

            // broadcast h (lanes 0..24 hold valid h) -> uniform hv
#pragma unroll
            for (int j = 0; j < 13; ++j) {
                hv[j].x = bcast(h, 2 * j);
                hv[j].y = (2 * j + 1 < Hn) ? bcast(h, 2 * j + 1) : 0.f;
            }
        }
    }
}

// ---------------- kernel 3: fused FC, memory-bound ----------------
template <typename ST>
__global__ __launch_bounds__(256, 4)
void fc_gemm(const ST* __restrict__ gws, const float* __restrict__ W_fc,
             const float* __restrict__ b_fc, float* __restrict__ out) {
    __shared__ float lw[On * Hn];   // 64 x 25
    __shared__ float lb[On];
    __shared__ float lh[64 * Hn];   // 64 rows of h

    const int tid = threadIdx.x;
    const size_t row0 = (size_t)blockIdx.x * 64;

    for (int i = tid; i < On * Hn; i += 256) lw[i] = W_fc[i];
    if (tid < On) lb[tid] = b_fc[tid];
    for (int i = tid; i < 64 * Hn; i += 256) {
        const int r = i / Hn, j = i - r * Hn;
        lh[i] = (float)gws[(row0 + r) * ROW + j];
    }
    __syncthreads();

#pragma unroll
    for (int it = 0; it < 16; ++it) {
        const int idx = it * 256 + tid;
        const int r = idx >> 6, o = idx & 63;
        float a0 = lb[o], a1 = 0.f;
#pragma unroll
        for (int j = 0; j < 24; j += 2) {
            a0 += lw[o * Hn + j + 0] * lh[r * Hn + j + 0];
            a1 += lw[o * Hn + j + 1] * lh[r * Hn + j + 1];
        }
        a0 += lw[o * Hn + 24] * lh[r * Hn + 24];
        out[(row0 + r) * On + o] = a0 + a1;
    }
}

extern "C" void kernel_launch(void* const* d_in, const int* in_sizes, int n_in,
                              void* d_out, int out_size, void* d_ws, size_t ws_size,
                              hipStream_t stream) {
    const float* x    = (const float*)d_in[0];
    const float* W_ih = (const float*)d_in[1];
    const float* W_hh = (const float*)d_in[2];
    const float* b_ih = (const float*)d_in[3];
    const float* b_hh = (const float*)d_in[4];
    const float* W_fc = (const float*)d_in[5];
    const float* b_fc = (const float*)d_in[6];
    float* out = (float*)d_out;

    const size_t need_f32 = (size_t)BT * ROW * sizeof(float);   // 104.9 MB
    const int nb1 = BT / 64;                                    // 4096
    const int nb3 = BT / 64;                                    // 4096

    if (ws_size >= need_f32) {
        float* gws = (float*)d_ws;
        gates_mfma<float><<<nb1, 256, 0, stream>>>(x, W_ih, b_ih, b_hh, gws);
        lstm_rec6<float><<<Bn, 64, 0, stream>>>(gws, W_hh);
        fc_gemm<float><<<nb3, 256, 0, stream>>>(gws, W_fc, b_fc, out);
    } else {
        __half* gws = (__half*)d_ws;
        gates_mfma<__half><<<nb1, 256, 0, stream>>>(x, W_ih, b_ih, b_hh, gws);
        lstm_rec6<__half><<<Bn, 64, 0, stream>>>(gws, W_hh);
        fc_gemm<__half><<<nb3, 256, 0, stream>>>(gws, W_fc, b_fc, out);
    }
}

// Round 4
// 395.739 us; speedup vs baseline: 1.3196x; 1.0971x over previous
//
#include <hip/hip_runtime.h>
#include <hip/hip_fp16.h>

// LSTM: B=256, T=1024, I=64, H=25 (4H=100), O=64. fp32 in/out.
//
// R4: fuse FC into the recurrence kernel; delete k3; h never hits memory.
//   Evidence (R3 counters): lstm_rec6 532 cyc/step, VALUBusy 15% -> ~450
//   stall cycles/step. Causes: (1) h-store into gws aliases the gate loads
//   -> compiler orders them (vmcnt drain/step), defeating the 8-deep ring;
//   (2) __shfl_xor = ds_bpermute (~60-120 cy LDS latency) on the c-chain.
//   Fix: (1) gws is now READ-ONLY in k2 (h stays in registers; FC output
//   written straight to `out`, a distinct restrict pointer -> no ordering);
//   (2) v_permlane32_swap_b32 returning the b operand: under both candidate
//   semantics (and under a==b regalloc coalescing) b's LOW lanes receive the
//   high-half value - the only lanes whose c/h are kept. (R2's failure was
//   returning `a`, whose low lanes are unchanged in all models.)
// Carried from R1-R3:
//   - gates split across wave halves: lanes 0..31 own (i,g) of unit r,
//     lanes 32..63 own (f,o); 52 weight VGPRs; 26 pk_fma/step.
//   - exp2 scale folding (k1 pre-scales gws by -log2e / -2log2e).
//   - gws cols 0..49 = (i,g) interleaved, 50..99 = (f,o): one dwordx2
//     per lane per step; 8-deep prefetch ring.
//   - FC fused: hv is wave-uniform after broadcast; lane o=lane computes
//     dot25(h, W_fc[o,:]) + b_fc[o]; 64-lane coalesced 256B store per step.

#define Bn 256
#define Tn 1024
#define In 64
#define Hn 25
#define Gn 100
#define On 64
#define BT (Bn * Tn)
#define ROW 100

#define SCL_S -1.44269504089f   // -log2(e)   : sigmoid gates (i,f,o)
#define SCL_T -2.88539008178f   // -2*log2(e) : tanh gate (g)

typedef __attribute__((ext_vector_type(8))) short short8;
typedef __attribute__((ext_vector_type(4))) float f32x4;
typedef __attribute__((ext_vector_type(2))) float f32x2;

__device__ __forceinline__ float frcp(float x) { return __builtin_amdgcn_rcpf(x); }
__device__ __forceinline__ float ex2(float x) {
    // raw v_exp_f32 (2^x); s_nop 1 covers the trans->VALU consumer hazard
    // the compiler cannot see through the asm block.
    float r;
    asm("v_exp_f32 %0, %1\n\ts_nop 1" : "=v"(r) : "v"(x));
    return r;
}
__device__ __forceinline__ float bcast(float v, int lane) {
    return __int_as_float(__builtin_amdgcn_readlane(__float_as_int(v), lane));
}
__device__ __forceinline__ float xswap(float x) {
    // v_permlane32_swap_b32 a, b exchanges a.row1 (lanes 32-63) with
    // b.row0 (lanes 0-31).  With a=b=x, the returned *b* holds, in its
    // low lanes, x from lanes 32-63 (true under both orientation models,
    // and under a==b register coalescing -> full swap).  Low lanes are
    // the only ones whose downstream c/h we keep.
    float a = x, b = x;
    asm("s_nop 0\n\tv_permlane32_swap_b32 %0, %1\n\ts_nop 0"
        : "+v"(a), "+v"(b));
    return b;
}
__device__ __forceinline__ short f2bf(float f) {   // RNE fp32 -> bf16 bits
    unsigned u = __float_as_uint(f);
    unsigned r = (u + 0x7FFFu + ((u >> 16) & 1u)) >> 16;
    return (short)r;
}

// gws column map: n<50: unit n>>1, gate i (even) / g (odd);
//                 n>=50: m=n-50, unit m>>1, gate f (even) / o (odd).
__device__ __forceinline__ void colmap(int n, int& g, float& scl) {
    if (n < 50) {
        const int r = n >> 1;
        g = ((n & 1) ? 2 : 0) * Hn + r;
        scl = (n & 1) ? SCL_T : SCL_S;
    } else {
        const int m = n - 50, r = m >> 1;
        g = ((m & 1) ? 3 : 1) * Hn + r;
        scl = SCL_S;
    }
}

// ---------------- kernel 1: input GEMM via MFMA ----------------
template <typename ST>
__global__ __launch_bounds__(256, 4)
void gates_mfma(const float* __restrict__ x, const float* __restrict__ W_ih,
                const float* __restrict__ b_ih, const float* __restrict__ b_hh,
                ST* __restrict__ gws) {
    __shared__ short lA[64 * 72];
    __shared__ short lB[112 * 72];
    __shared__ float lbias[112];

    const int tid = threadIdx.x;
    const size_t row0 = (size_t)blockIdx.x * 64;

    for (int i = tid; i < 64 * 64; i += 256) {
        const int r = i >> 6, k = i & 63;
        lA[r * 72 + k] = f2bf(x[(row0 + r) * In + k]);
    }
    for (int i = tid; i < 112 * 64; i += 256) {
        const int n = i >> 6, k = i & 63;
        float v = 0.f;
        if (n < Gn) {
            int g; float scl;
            colmap(n, g, scl);
            v = W_ih[(size_t)g * In + k] * scl;   // scale folded pre-bf16
        }
        lB[n * 72 + k] = f2bf(v);
    }
    if (tid < 112) {
        float v = 0.f;
        if (tid < Gn) {
            int g; float scl;
            colmap(tid, g, scl);
            v = (b_ih[g] + b_hh[g]) * scl;
        }
        lbias[tid] = v;
    }
    __syncthreads();

    const int wave = tid >> 6;
    const int lane = tid & 63;
    const int quad = lane >> 4;
    const int l16  = lane & 15;
    const int arow = wave * 16 + l16;

    const short8 a0 = *(const short8*)&lA[arow * 72 + 0  + quad * 8];
    const short8 a1 = *(const short8*)&lA[arow * 72 + 32 + quad * 8];

#pragma unroll
    for (int nt = 0; nt < 7; ++nt) {
        const int col = nt * 16 + l16;
        const short8 b0 = *(const short8*)&lB[col * 72 + 0  + quad * 8];
        const short8 b1 = *(const short8*)&lB[col * 72 + 32 + quad * 8];
        const float bias = lbias[col];
        f32x4 acc = {bias, bias, bias, bias};
        acc = __builtin_amdgcn_mfma_f32_16x16x32_bf16(a0, b0, acc, 0, 0, 0);
        acc = __builtin_amdgcn_mfma_f32_16x16x32_bf16(a1, b1, acc, 0, 0, 0);
        if (col < Gn) {
#pragma unroll
            for (int i = 0; i < 4; ++i) {
                const size_t grow = row0 + wave * 16 + quad * 4 + i;
                gws[grow * ROW + col] = (ST)acc[i];
            }
        }
    }
}

// ---------------- kernel 2: recurrence + fused FC, 1 wave / batch --------
template <typename ST> struct G2;
template <> struct G2<float> {
    static __device__ __forceinline__ float2 ld(const float* p) {
        return *(const float2*)p;
    }
};
template <> struct G2<__half> {
    static __device__ __forceinline__ float2 ld(const __half* p) {
        ushort2 u = *(const ushort2*)p;
        __half a, b;
        *(unsigned short*)&a = u.x; *(unsigned short*)&b = u.y;
        return make_float2((float)a, (float)b);
    }
};

__device__ __forceinline__ float dot25v(const f32x2* w, const f32x2* hv) {
    f32x2 a0 = w[0] * hv[0];          // pk_mul start: no acc-init movs
    f32x2 a1 = w[1] * hv[1];
#pragma unroll
    for (int j = 2; j < 13; j += 2) a0 += w[j] * hv[j];   // 6 pk_fma, chain 7
#pragma unroll
    for (int j = 3; j < 13; j += 2) a1 += w[j] * hv[j];   // 5 pk_fma, chain 6
    f32x2 s = a0 + a1;
    return s.x + s.y;
}

template <typename ST>
__global__ __launch_bounds__(64, 1)
void lstm_rec7(const ST* __restrict__ gws, const float* __restrict__ W_hh,
               const float* __restrict__ W_fc, const float* __restrict__ b_fc,
               float* __restrict__ out) {
    const int lane = threadIdx.x;
    const bool lo  = lane < 32;
    const int rr   = min(lane & 31, Hn - 1);
    const int b    = blockIdx.x;

    // this lane's two gates: A = i (lo) / f (hi), B = g (lo) / o (hi)
    const float sclA = SCL_S;
    const float sclB = lo ? SCL_T : SCL_S;
    const float sB   = lo ? 2.f : 1.f;     // tanh = 2*sigm(2x)-1
    const float dB   = lo ? -1.f : 0.f;
    const float* rowA = W_hh + (size_t)((lo ? 0 : 1) * Hn + rr) * Hn;
    const float* rowB = W_hh + (size_t)((lo ? 2 : 3) * Hn + rr) * Hn;

    f32x2 wA[13], wB[13];   // recurrent weights, 52 regs
#pragma unroll
    for (int j = 0; j < 13; ++j) {
        const int j0 = 2 * j, j1 = 2 * j + 1;
        wA[j].x = rowA[j0] * sclA;
        wA[j].y = (j1 < Hn) ? rowA[j1] * sclA : 0.f;
        wB[j].x = rowB[j0] * sclB;
        wB[j].y = (j1 < Hn) ? rowB[j1] * sclB : 0.f;
    }

    // fused-FC weights: lane owns output unit o = lane (all 64 lanes useful)
    f32x2 wFC[13];
#pragma unroll
    for (int j = 0; j < 13; ++j) {
        const int j0 = 2 * j, j1 = 2 * j + 1;
        wFC[j].x = W_fc[(size_t)lane * Hn + j0];
        wFC[j].y = (j1 < Hn) ? W_fc[(size_t)lane * Hn + j1] : 0.f;
    }
    const float bfc = b_fc[lane];

    const int coff = 2 * rr + (lo ? 0 : 50);                 // element offset in row
    const ST* gp = gws + (size_t)b * Tn * ROW + coff;        // dwordx2 gate loads
    float*    op = out + (size_t)b * Tn * On + lane;         // FC output stores

    f32x2 hv[13];
#pragma unroll
    for (int j = 0; j < 13; ++j) hv[j] = (f32x2){0.f, 0.f};
    float c = 0.f;

    float2 ring[8];                                          // 8-deep prefetch
#pragma unroll
    for (int s = 0; s < 8; ++s) ring[s] = G2<ST>::ld(gp + (size_t)s * ROW);

#pragma unroll 1
    for (int t0 = 0; t0 < Tn; t0 += 8) {
        // last block re-loads rows Tn-8..Tn-1 (never consumed; harmless)
        const int tp0 = (t0 + 8 <= Tn - 8) ? (t0 + 8) : (Tn - 8);
#pragma unroll
        for (int s = 0; s < 8; ++s) {
            const int t = t0 + s;

            const float2 nxt = G2<ST>::ld(gp + (size_t)(tp0 + s) * ROW);

            float aA = dot25v(wA, hv);
            float aB = dot25v(wB, hv);
            aA += ring[s].x;            // vmcnt wait lands here, after the dot
            aB += ring[s].y;
            ring[s] = nxt;

            const float actA = frcp(1.f + ex2(aA));            // I (lo) / F (hi)
            const float actB = sB * frcp(1.f + ex2(aB)) + dB;  // G (lo) / O (hi)
            const float Fg = xswap(actA);   // low lanes: F of same unit
            const float Og = xswap(actB);   // low lanes: O of same unit
            c = Fg * c + actA * actB;       // valid in lanes 0..24
            const float th = 2.f * frcp(1.f + ex2(c * SCL_T)) - 1.f;  // tanh(c)
            const float h  = Og * th;

            // broadcast h (lanes 0..24 hold valid h) -> wave-uniform hv
#pragma unroll
            for (int j = 0; j < 13; ++j) {
                hv[j].x = bcast(h, 2 * j);
                hv[j].y = (2 * j + 1 < Hn) ? bcast(h, 2 * j + 1) : 0.f;
            }

            // fused FC: out[b,t,lane] = dot25(h, W_fc[lane,:]) + b_fc[lane].
            // Independent of the next step's recurrence chain -> fills
            // stall cycles; 64-lane coalesced 256B store.
            {
                f32x2 f0 = wFC[0] * hv[0];
                f32x2 f1 = wFC[1] * hv[1];
#pragma unroll
                for (int j = 2; j < 13; j += 2) f0 += wFC[j] * hv[j];
#pragma unroll
                for (int j = 3; j < 13; j += 2) f1 += wFC[j] * hv[j];
                f32x2 fs = f0 + f1;
                op[(size_t)t * On] = fs.x + fs.y + bfc;
            }
        }
    }
}

extern "C" void kernel_launch(void* const* d_in, const int* in_sizes, int n_in,
                              void* d_out, int out_size, void* d_ws, size_t ws_size,
                              hipStream_t stream) {
    const float* x    = (const float*)d_in[0];
    const float* W_ih = (const float*)d_in[1];
    const float* W_hh = (const float*)d_in[2];
    const float* b_ih = (const float*)d_in[3];
    const float* b_hh = (const float*)d_in[4];
    const float* W_fc = (const float*)d_in[5];
    const float* b_fc = (const float*)d_in[6];
    float* out = (float*)d_out;

    const size_t need_f32 = (size_t)BT * ROW * sizeof(float);   // 104.9 MB
    const int nb1 = BT / 64;                                    // 4096

    if (ws_size >= need_f32) {
        float* gws = (float*)d_ws;
        gates_mfma<float><<<nb1, 256, 0, stream>>>(x, W_ih, b_ih, b_hh, gws);
        lstm_rec7<float><<<Bn, 64, 0, stream>>>(gws, W_hh, W_fc, b_fc, out);
    } else {
        __half* gws = (__half*)d_ws;
        gates_mfma<__half><<<nb1, 256, 0, stream>>>(x, W_ih, b_ih, b_hh, gws);
        lstm_rec7<__half><<<Bn, 64, 0, stream>>>(gws, W_hh, W_fc, b_fc, out);
    }
}

// Round 5
// 387.184 us; speedup vs baseline: 1.3488x; 1.0221x over previous
//
#include <hip/hip_runtime.h>
#include <hip/hip_fp16.h>

// LSTM: B=256, T=1024, I=64, H=25 (4H=100), O=64. fp32 in/out.
//
// R5 theory (from R4 counters): rec7 575 cy/step, VALUBusy 18% -> ~470
//   constant stall. Both rec6 (h-store) and rec7 (FC-store) issue ONE global
//   store per step whose source VGPR is recomputed next step. VMEM stores
//   read source VGPRs asynchronously; rewriting a pending store's source reg
//   forces s_waitcnt vmcnt covering that store = full memory-completion
//   round trip (~450 cy) EVERY step. Fix: batch FC results into fcv[2][8]
//   (double-buffered 8-step half-blocks), issue stores between half-blocks
//   -> store->rewrite distance 16 steps >> store latency -> wait is free.
// Also: k1's per-block W_ih staging (colmap+scale+f2bf, ~220 VALU/thread,
//   identical across 4096 blocks) hoisted into a one-time prep kernel
//   writing permuted scaled bf16 W + bias into the ws tail (14.8 KB).
// Carried: gate split across wave halves (52 weight VGPR), exp2 scale
//   folding, (i,g)/(f,o) column layout -> one dwordx2/lane/step, 8-deep
//   ring, v_permlane32_swap_b32 (return b operand; validated R4), fused FC.

#define Bn 256
#define Tn 1024
#define In 64
#define Hn 25
#define Gn 100
#define On 64
#define BT (Bn * Tn)
#define ROW 100

#define SCL_S -1.44269504089f   // -log2(e)   : sigmoid gates (i,f,o)
#define SCL_T -2.88539008178f   // -2*log2(e) : tanh gate (g)

typedef __attribute__((ext_vector_type(8))) short short8;
typedef __attribute__((ext_vector_type(4))) float f32x4;
typedef __attribute__((ext_vector_type(2))) float f32x2;

__device__ __forceinline__ float frcp(float x) { return __builtin_amdgcn_rcpf(x); }
__device__ __forceinline__ float ex2(float x) {
    // raw v_exp_f32 (2^x); s_nop 1 covers the trans->VALU consumer hazard
    // the compiler cannot see through the asm block.
    float r;
    asm("v_exp_f32 %0, %1\n\ts_nop 1" : "=v"(r) : "v"(x));
    return r;
}
__device__ __forceinline__ float bcast(float v, int lane) {
    return __int_as_float(__builtin_amdgcn_readlane(__float_as_int(v), lane));
}
__device__ __forceinline__ float xswap(float x) {
    // v_permlane32_swap_b32 a, b: returned b's LOW lanes hold the high-half
    // value (only low lanes' c/h are kept downstream). Validated in R4
    // (passed, absmax 0.0039). s_nop covers the VALU->permlane hazard.
    float a = x, b = x;
    asm("s_nop 0\n\tv_permlane32_swap_b32 %0, %1\n\ts_nop 0"
        : "+v"(a), "+v"(b));
    return b;
}
__device__ __forceinline__ short f2bf(float f) {   // RNE fp32 -> bf16 bits
    unsigned u = __float_as_uint(f);
    unsigned r = (u + 0x7FFFu + ((u >> 16) & 1u)) >> 16;
    return (short)r;
}

// gws column map: n<50: unit n>>1, gate i (even) / g (odd);
//                 n>=50: m=n-50, unit m>>1, gate f (even) / o (odd).
__device__ __forceinline__ void colmap(int n, int& g, float& scl) {
    if (n < 50) {
        const int r = n >> 1;
        g = ((n & 1) ? 2 : 0) * Hn + r;
        scl = (n & 1) ? SCL_T : SCL_S;
    } else {
        const int m = n - 50, r = m >> 1;
        g = ((m & 1) ? 3 : 1) * Hn + r;
        scl = SCL_S;
    }
}

// ---------------- kernel 0: one-time W/bias prep (14.8 KB in ws tail) ----
__global__ __launch_bounds__(256)
void prep_w(const float* __restrict__ W_ih, const float* __restrict__ b_ih,
            const float* __restrict__ b_hh, short* __restrict__ wprep,
            float* __restrict__ bprep) {
    const int tid = threadIdx.x;
    for (int i = tid; i < 112 * 64; i += 256) {
        const int n = i >> 6, k = i & 63;
        float v = 0.f;
        if (n < Gn) {
            int g; float scl;
            colmap(n, g, scl);
            v = W_ih[(size_t)g * In + k] * scl;
        }
        wprep[i] = f2bf(v);
    }
    if (tid < 112) {
        float v = 0.f;
        if (tid < Gn) {
            int g; float scl;
            colmap(tid, g, scl);
            v = (b_ih[g] + b_hh[g]) * scl;
        }
        bprep[tid] = v;
    }
}

// ---------------- kernel 1: input GEMM via MFMA ----------------
template <typename ST, bool PREP>
__global__ __launch_bounds__(256, 4)
void gates_mfma(const float* __restrict__ x, const float* __restrict__ W_ih,
                const float* __restrict__ b_ih, const float* __restrict__ b_hh,
                const short* __restrict__ wprep, const float* __restrict__ bprep,
                ST* __restrict__ gws) {
    __shared__ short lA[64 * 72];
    __shared__ short lB[112 * 72];
    __shared__ float lbias[112];

    const int tid = threadIdx.x;
    const size_t row0 = (size_t)blockIdx.x * 64;

    for (int i = tid; i < 64 * 64; i += 256) {
        const int r = i >> 6, k = i & 63;
        lA[r * 72 + k] = f2bf(x[(row0 + r) * In + k]);
    }
    if (PREP) {
        // copy pre-permuted/scaled bf16 weights (L2-resident, int-granular)
        for (int i = tid; i < 112 * 32; i += 256) {
            const int j = 2 * i, n = j >> 6, k = j & 63;
            *(int*)&lB[n * 72 + k] = ((const int*)wprep)[i];
        }
        if (tid < 112) lbias[tid] = bprep[tid];
    } else {
        for (int i = tid; i < 112 * 64; i += 256) {
            const int n = i >> 6, k = i & 63;
            float v = 0.f;
            if (n < Gn) {
                int g; float scl;
                colmap(n, g, scl);
                v = W_ih[(size_t)g * In + k] * scl;
            }
            lB[n * 72 + k] = f2bf(v);
        }
        if (tid < 112) {
            float v = 0.f;
            if (tid < Gn) {
                int g; float scl;
                colmap(tid, g, scl);
                v = (b_ih[g] + b_hh[g]) * scl;
            }
            lbias[tid] = v;
        }
    }
    __syncthreads();

    const int wave = tid >> 6;
    const int lane = tid & 63;
    const int quad = lane >> 4;
    const int l16  = lane & 15;
    const int arow = wave * 16 + l16;

    const short8 a0 = *(const short8*)&lA[arow * 72 + 0  + quad * 8];
    const short8 a1 = *(const short8*)&lA[arow * 72 + 32 + quad * 8];

#pragma unroll
    for (int nt = 0; nt < 7; ++nt) {
        const int col = nt * 16 + l16;
        const short8 b0 = *(const short8*)&lB[col * 72 + 0  + quad * 8];
        const short8 b1 = *(const short8*)&lB[col * 72 + 32 + quad * 8];
        const float bias = lbias[col];
        f32x4 acc = {bias, bias, bias, bias};
        acc = __builtin_amdgcn_mfma_f32_16x16x32_bf16(a0, b0, acc, 0, 0, 0);
        acc = __builtin_amdgcn_mfma_f32_16x16x32_bf16(a1, b1, acc, 0, 0, 0);
        if (col < Gn) {
#pragma unroll
            for (int i = 0; i < 4; ++i) {
                const size_t grow = row0 + wave * 16 + quad * 4 + i;
                gws[grow * ROW + col] = (ST)acc[i];
            }
        }
    }
}

// ---------------- kernel 2: recurrence + fused FC, 1 wave / batch --------
template <typename ST> struct G2;
template <> struct G2<float> {
    static __device__ __forceinline__ float2 ld(const float* p) {
        return *(const float2*)p;
    }
};
template <> struct G2<__half> {
    static __device__ __forceinline__ float2 ld(const __half* p) {
        ushort2 u = *(const ushort2*)p;
        __half a, b;
        *(unsigned short*)&a = u.x; *(unsigned short*)&b = u.y;
        return make_float2((float)a, (float)b);
    }
};

__device__ __forceinline__ float dot25v(const f32x2* w, const f32x2* hv) {
    f32x2 a0 = w[0] * hv[0];          // pk_mul start: no acc-init movs
    f32x2 a1 = w[1] * hv[1];
#pragma unroll
    for (int j = 2; j < 13; j += 2) a0 += w[j] * hv[j];   // 6 pk_fma, chain 7
#pragma unroll
    for (int j = 3; j < 13; j += 2) a1 += w[j] * hv[j];   // 5 pk_fma, chain 6
    f32x2 s = a0 + a1;
    return s.x + s.y;
}

template <typename ST>
__global__ __launch_bounds__(64, 1)
void lstm_rec8(const ST* __restrict__ gws, const float* __restrict__ W_hh,
               const float* __restrict__ W_fc, const float* __restrict__ b_fc,
               float* __restrict__ out) {
    const int lane = threadIdx.x;
    const bool lo  = lane < 32;
    const int rr   = min(lane & 31, Hn - 1);
    const int b    = blockIdx.x;

    // this lane's two gates: A = i (lo) / f (hi), B = g (lo) / o (hi)
    const float sclA = SCL_S;
    const float sclB = lo ? SCL_T : SCL_S;
    const float sB   = lo ? 2.f : 1.f;     // tanh = 2*sigm(2x)-1
    const float dB   = lo ? -1.f : 0.f;
    const float* rowA = W_hh + (size_t)((lo ? 0 : 1) * Hn + rr) * Hn;
    const float* rowB = W_hh + (size_t)((lo ? 2 : 3) * Hn + rr) * Hn;

    f32x2 wA[13], wB[13];   // recurrent weights, 52 regs
#pragma unroll
    for (int j = 0; j < 13; ++j) {
        const int j0 = 2 * j, j1 = 2 * j + 1;
        wA[j].x = rowA[j0] * sclA;
        wA[j].y = (j1 < Hn) ? rowA[j1] * sclA : 0.f;
        wB[j].x = rowB[j0] * sclB;
        wB[j].y = (j1 < Hn) ? rowB[j1] * sclB : 0.f;
    }

    // fused-FC weights: lane owns output unit o = lane (all 64 lanes useful)
    f32x2 wFC[13];
#pragma unroll
    for (int j = 0; j < 13; ++j) {
        const int j0 = 2 * j, j1 = 2 * j + 1;
        wFC[j].x = W_fc[(size_t)lane * Hn + j0];
        wFC[j].y = (j1 < Hn) ? W_fc[(size_t)lane * Hn + j1] : 0.f;
    }
    const float bfc = b_fc[lane];

    const int coff = 2 * rr + (lo ? 0 : 50);                 // element offset in row
    const ST* gp = gws + (size_t)b * Tn * ROW + coff;        // dwordx2 gate loads
    float*    op = out + (size_t)b * Tn * On + lane;         // FC output stores

    f32x2 hv[13];
#pragma unroll
    for (int j = 0; j < 13; ++j) hv[j] = (f32x2){0.f, 0.f};
    float c = 0.f;

    float fcv[2][8];        // FC results, double-buffered by 8-step half
    float2 ring[8];         // 8-deep gate prefetch ring
#pragma unroll
    for (int s = 0; s < 8; ++s) ring[s] = G2<ST>::ld(gp + (size_t)s * ROW);

#pragma unroll 1
    for (int t0 = 0; t0 < Tn; t0 += 16) {
#pragma unroll
        for (int u = 0; u < 2; ++u) {
#pragma unroll
            for (int s = 0; s < 8; ++s) {
                const int t = t0 + u * 8 + s;

                // prefetch t+8 (ring slot s: step index mod 8 == s)
                int tp = t + 8; if (tp > Tn - 1) tp = Tn - 1;
                const float2 nxt = G2<ST>::ld(gp + (size_t)tp * ROW);

                float aA = dot25v(wA, hv);
                float aB = dot25v(wB, hv);
                aA += ring[s].x;        // vmcnt wait: ring[s] loaded 8 steps ago
                aB += ring[s].y;
                ring[s] = nxt;

                const float actA = frcp(1.f + ex2(aA));            // I (lo) / F (hi)
                const float actB = sB * frcp(1.f + ex2(aB)) + dB;  // G (lo) / O (hi)
                const float Fg = xswap(actA);   // low lanes: F of same unit
                const float Og = xswap(actB);   // low lanes: O of same unit
                c = Fg * c + actA * actB;       // valid in lanes 0..24
                const float th = 2.f * frcp(1.f + ex2(c * SCL_T)) - 1.f;  // tanh(c)
                const float h  = Og * th;

                // broadcast h (lanes 0..24 hold valid h) -> wave-uniform hv
#pragma unroll
                for (int j = 0; j < 13; ++j) {
                    hv[j].x = bcast(h, 2 * j);
                    hv[j].y = (2 * j + 1 < Hn) ? bcast(h, 2 * j + 1) : 0.f;
                }

                // fused FC into a register, NOT memory (store-WAW fix)
                {
                    f32x2 f0 = wFC[0] * hv[0];
                    f32x2 f1 = wFC[1] * hv[1];
#pragma unroll
                    for (int j = 2; j < 13; j += 2) f0 += wFC[j] * hv[j];
#pragma unroll
                    for (int j = 3; j < 13; j += 2) f1 += wFC[j] * hv[j];
                    f32x2 fs = f0 + f1;
                    fcv[u][s] = fs.x + fs.y + bfc;
                }
            }
            // batch the 8 stores; fcv[u][*] not rewritten for 16 more steps,
            // so the store-source WAW wait is satisfied long before then.
#pragma unroll
            for (int s = 0; s < 8; ++s)
                op[(size_t)(t0 + u * 8 + s) * On] = fcv[u][s];
        }
    }
}

extern "C" void kernel_launch(void* const* d_in, const int* in_sizes, int n_in,
                              void* d_out, int out_size, void* d_ws, size_t ws_size,
                              hipStream_t stream) {
    const float* x    = (const float*)d_in[0];
    const float* W_ih = (const float*)d_in[1];
    const float* W_hh = (const float*)d_in[2];
    const float* b_ih = (const float*)d_in[3];
    const float* b_hh = (const float*)d_in[4];
    const float* W_fc = (const float*)d_in[5];
    const float* b_fc = (const float*)d_in[6];
    float* out = (float*)d_out;

    const size_t need_f32 = (size_t)BT * ROW * sizeof(float);   // 104.9 MB
    const size_t need_h   = (size_t)BT * ROW * sizeof(__half);  //  52.4 MB
    const size_t PREPB    = 16384;                              // W(14336)+b(448)
    const int nb1 = BT / 64;                                    // 4096

    if (ws_size >= need_f32) {
        float* gws = (float*)d_ws;
        if (ws_size >= need_f32 + PREPB) {
            short* wprep = (short*)((char*)d_ws + need_f32);
            float* bprep = (float*)(wprep + 112 * 64);
            prep_w<<<1, 256, 0, stream>>>(W_ih, b_ih, b_hh, wprep, bprep);
            gates_mfma<float, true><<<nb1, 256, 0, stream>>>(
                x, W_ih, b_ih, b_hh, wprep, bprep, gws);
        } else {
            gates_mfma<float, false><<<nb1, 256, 0, stream>>>(
                x, W_ih, b_ih, b_hh, nullptr, nullptr, gws);
        }
        lstm_rec8<float><<<Bn, 64, 0, stream>>>(gws, W_hh, W_fc, b_fc, out);
    } else {
        __half* gws = (__half*)d_ws;
        if (ws_size >= need_h + PREPB) {
            short* wprep = (short*)((char*)d_ws + need_h);
            float* bprep = (float*)(wprep + 112 * 64);
            prep_w<<<1, 256, 0, stream>>>(W_ih, b_ih, b_hh, wprep, bprep);
            gates_mfma<__half, true><<<nb1, 256, 0, stream>>>(
                x, W_ih, b_ih, b_hh, wprep, bprep, gws);
        } else {
            gates_mfma<__half, false><<<nb1, 256, 0, stream>>>(
                x, W_ih, b_ih, b_hh, nullptr, nullptr, gws);
        }
        lstm_rec8<__half><<<Bn, 64, 0, stream>>>(gws, W_hh, W_fc, b_fc, out);
    }
}